// Round 4
// baseline (343.720 us; speedup 1.0000x reference)
//
#include <hip/hip_runtime.h>
#include <hip/hip_bf16.h>
#include <math.h>

#define H_ 1024
#define NH_ 16
#define HD_ 64
#define B_ 2
#define SQ_ 2048
#define SK_ 2048

using bf16x8 = __attribute__((ext_vector_type(8))) short;
using f32x4  = __attribute__((ext_vector_type(4))) float;

static __device__ __forceinline__ unsigned short f2bf(float f) {
  union { float f; unsigned u; } v; v.f = f;
  unsigned r = v.u + 0x7fffu + ((v.u >> 16) & 1u);
  return (unsigned short)(r >> 16);
}

// pack two f32 -> two bf16 (round-half-up) in one dword: [a(lo), b(hi)]
static __device__ __forceinline__ unsigned pack_bf(float a, float b) {
  union { float f; unsigned u; } ua, ub;
  ua.f = a; ub.f = b;
  return __builtin_amdgcn_perm(ub.u + 0x8000u, ua.u + 0x8000u, 0x07060302u);
}

static __device__ __forceinline__ void gl2lds16(const void* g, void* l) {
  __builtin_amdgcn_global_load_lds(
      (const __attribute__((address_space(1))) unsigned int*)g,
      (__attribute__((address_space(3))) unsigned int*)l, 16, 0, 0);
}

// swizzled index (shorts) within a [rows][64-short] tile, 128B rows
static __device__ __forceinline__ int sidx(int row, int cbyte) {
  return row * 64 + (((cbyte) ^ ((row & 7) << 4)) >> 1);
}

// ---------------- f32 -> bf16 convert (8 elems/thread) ----------------
__global__ __launch_bounds__(256) void conv_bf16(
    const float* __restrict__ src, unsigned short* __restrict__ dst,
    int rows, int cols, int ld_src, int ld_dst) {
  long total = (long)rows * cols / 8;
  for (long i = blockIdx.x * (long)blockDim.x + threadIdx.x; i < total;
       i += (long)gridDim.x * blockDim.x) {
    long e = i * 8;
    int r = (int)(e / cols);
    int c = (int)(e % cols);
    const float* s = src + (long)r * ld_src + c;
    unsigned short tmp[8];
#pragma unroll
    for (int j = 0; j < 8; ++j) tmp[j] = f2bf(s[j]);
    *(uint4*)(dst + (long)r * ld_dst + c) = *(uint4*)tmp;
  }
}

// ---------------- f32 (R,C) -> bf16 transposed (C,R) ----------------
__global__ __launch_bounds__(256) void convT(
    const float* __restrict__ in, unsigned short* __restrict__ out, int R, int C) {
  __shared__ __align__(16) unsigned short Ls[64][68];
  int nct = C >> 6;
  int tr = blockIdx.x / nct, tc = blockIdx.x % nct;
  int r0 = tr * 64, c0 = tc * 64;
  int rr = threadIdx.x >> 4;
  int cc = (threadIdx.x & 15) * 4;
#pragma unroll
  for (int i = 0; i < 4; ++i) {
    int r = rr + 16 * i;
    float4 v = *(const float4*)&in[(long)(r0 + r) * C + c0 + cc];
    unsigned short t[4] = {f2bf(v.x), f2bf(v.y), f2bf(v.z), f2bf(v.w)};
    *(unsigned long long*)&Ls[r][cc] = *(unsigned long long*)t;
  }
  __syncthreads();
  int oc = threadIdx.x >> 2;
  int orr = (threadIdx.x & 3) * 16;
  unsigned short t[16];
#pragma unroll
  for (int j = 0; j < 16; ++j) t[j] = Ls[orr + j][oc];
  *(uint4*)&out[(long)(c0 + oc) * R + r0 + orr] = *(uint4*)&t[0];
  *(uint4*)&out[(long)(c0 + oc) * R + r0 + orr + 8] = *(uint4*)&t[8];
}

// ---------------- bf16 GEMM, B^T input, BK=64, double-buffered, swizzled ----
// Out = A(MxK) @ W(KxN) + bias, Bw = W^T (N rows, K cols). BN = NF*32.
// MODE 0: bf16 out0.  MODE 1: f32 out0 + GELU.  MODE 2: split KV (col<H ->
// bf16 K*mask to out0; col>=H -> V transposed to out1 (B,NH,HD,SK)).
template <int NF, int MODE>
__global__ __launch_bounds__(256) void gemm_bt(
    const unsigned short* __restrict__ A, int lda,
    const unsigned short* __restrict__ Bw, int ldb,
    const float* __restrict__ bias, const int* __restrict__ msk,
    void* __restrict__ out0, void* __restrict__ out1, int ldo,
    int M, int N, int K) {
  __shared__ __align__(16) unsigned short Al[2][128 * 64];
  __shared__ __align__(16) unsigned short Bl[2][NF * 32 * 64];
  const int tid = threadIdx.x;
  const int l = tid & 63, w = tid >> 6;
  const int wr = w >> 1, wc = w & 1;
  const int lq = l & 15, lh = l >> 4;
  const int m0 = blockIdx.y * 128, n0 = blockIdx.x * (NF * 32);

  // pre-swizzled global source (rule #21: linear LDS dest + inv-swizzled src)
  const int swcol = (((tid & 7) ^ ((tid >> 3) & 7)) << 3);  // shorts
  const int rbase = w * 8 + (l >> 3);
  const unsigned short* gA = A + (long)(m0 + rbase) * lda + swcol;
  const unsigned short* gB = Bw + (long)(n0 + rbase) * ldb + swcol;

  f32x4 acc[4][NF];
#pragma unroll
  for (int a = 0; a < 4; ++a)
#pragma unroll
    for (int b = 0; b < NF; ++b) acc[a][b] = (f32x4){0.f, 0.f, 0.f, 0.f};

  auto stage = [&](int k0, int buf) {
#pragma unroll
    for (int i = 0; i < 4; ++i)
      gl2lds16(gA + (long)(i * 32) * lda + k0, &Al[buf][i * 2048 + w * 512]);
#pragma unroll
    for (int i = 0; i < NF; ++i)
      gl2lds16(gB + (long)(i * 32) * ldb + k0, &Bl[buf][i * 2048 + w * 512]);
  };

  const int NT = K >> 6;
  stage(0, 0);
  __syncthreads();
  int cur = 0;
  for (int t = 0; t < NT; ++t) {
    if (t + 1 < NT) stage((t + 1) << 6, cur ^ 1);
    bf16x8 af[4][2], bfr[NF][2];
#pragma unroll
    for (int a = 0; a < 4; ++a) {
      int row = wr * 64 + a * 16 + lq;
#pragma unroll
      for (int kk = 0; kk < 2; ++kk)
        af[a][kk] = *(const bf16x8*)&Al[cur][sidx(row, kk * 64 + lh * 16)];
    }
#pragma unroll
    for (int b = 0; b < NF; ++b) {
      int row = wc * (NF * 16) + b * 16 + lq;
#pragma unroll
      for (int kk = 0; kk < 2; ++kk)
        bfr[b][kk] = *(const bf16x8*)&Bl[cur][sidx(row, kk * 64 + lh * 16)];
    }
#pragma unroll
    for (int kk = 0; kk < 2; ++kk)
#pragma unroll
      for (int a = 0; a < 4; ++a)
#pragma unroll
        for (int b = 0; b < NF; ++b)
          acc[a][b] = __builtin_amdgcn_mfma_f32_16x16x32_bf16(
              af[a][kk], bfr[b][kk], acc[a][b], 0, 0, 0);
    __syncthreads();
    cur ^= 1;
  }

#pragma unroll
  for (int a = 0; a < 4; ++a) {
#pragma unroll
    for (int bb = 0; bb < NF; ++bb) {
      int col = n0 + wc * (NF * 16) + bb * 16 + lq;
      float bv = bias[col];
      int row0 = m0 + wr * 64 + a * 16 + lh * 4;
      if (MODE == 0) {
        unsigned short* O = (unsigned short*)out0;
#pragma unroll
        for (int r = 0; r < 4; ++r)
          O[(long)(row0 + r) * ldo + col] = f2bf(acc[a][bb][r] + bv);
      } else if (MODE == 1) {
        float* O = (float*)out0;
#pragma unroll
        for (int r = 0; r < 4; ++r) {
          float v = acc[a][bb][r] + bv;
          float y = 0.7978845608028654f * (v + 0.044715f * v * v * v);
          O[(long)(row0 + r) * ldo + col] =
              v * __builtin_amdgcn_rcpf(1.f + __expf(-2.f * y));
        }
      } else {
        if (col < H_) {
          // K output, pre-masked: k-row index is row0+r (= b*SK + k)
          unsigned short* O = (unsigned short*)out0;
#pragma unroll
          for (int r = 0; r < 4; ++r) {
            float mk = (float)msk[row0 + r];
            O[(long)(row0 + r) * ldo + col] = f2bf((acc[a][bb][r] + bv) * mk);
          }
        } else {
          int vcol = col - H_, hh = vcol >> 6, dd = vcol & 63;
          int bi = row0 >> 11, k = row0 & 2047;
          unsigned short t[4];
#pragma unroll
          for (int r = 0; r < 4; ++r) t[r] = f2bf(acc[a][bb][r] + bv);
          *(unsigned long long*)((unsigned short*)out1 +
                                 (((long)(bi * NH_ + hh) * HD_ + dd) << 11) + k) =
              *(unsigned long long*)t;
        }
      }
    }
  }
}

// ---------------- flash attention, no-max softmax, global-direct K/V --------
// grid (SQ/64, NH, B), block 256 = 4 independent waves x 16 q-rows.
// K pre-masked (B*SK, H); V pre-transposed (B, NH, HD, SK). No barriers.
__global__ __launch_bounds__(256) void flash_attn(
    const unsigned short* __restrict__ Qb,
    const unsigned short* __restrict__ Kb,
    const unsigned short* __restrict__ Vtg,
    unsigned short* __restrict__ Ob) {
  __shared__ __align__(16) unsigned short Pl[4][1024];
  const int tid = threadIdx.x;
  const int l = tid & 63, w = tid >> 6;
  const int qb = blockIdx.x, h = blockIdx.y, b = blockIdx.z;
  const int lq = l & 15, lh = l >> 4;

  const long qrow = (long)b * SQ_ + qb * 64 + w * 16 + lq;
  const unsigned short* qp = Qb + qrow * H_ + h * HD_;
  const bf16x8 qf0 = *(const bf16x8*)(qp + lh * 8);
  const bf16x8 qf1 = *(const bf16x8*)(qp + 32 + lh * 8);

  // fragment bases: K row (k) = b*SK + lq (+16ms +64kt), col = h*64 + lh*8
  const unsigned short* Kg = Kb + ((long)b * SK_ + lq) * H_ + h * HD_ + lh * 8;
  // V row (d) = (b*NH+h)*64 + lq (+16ms), col (k) = lh*8 (+64kt)
  const unsigned short* Vg = Vtg + ((long)(b * NH_ + h) * HD_ + lq) * SK_ + lh * 8;

  unsigned short* Pw = Pl[w];
  const float C1 = 1.4426950408889634f;   // 1/ln2
  const float C2 = 23.083120654223414f;   // 16/ln2  (P = exp(s-16))

  float l_run = 0.f;
  f32x4 accO[4];
#pragma unroll
  for (int ms = 0; ms < 4; ++ms) accO[ms] = (f32x4){0.f, 0.f, 0.f, 0.f};

  const int NT = SK_ / 64;
  for (int kt = 0; kt < NT; ++kt) {
    const unsigned short* kbase = Kg + (long)kt * 64 * H_;
    const unsigned short* vbase = Vg + kt * 64;
    bf16x8 ka[4][2], va[4][2];
#pragma unroll
    for (int ms = 0; ms < 4; ++ms) {
      ka[ms][0] = *(const bf16x8*)(kbase + (long)ms * 16 * H_);
      ka[ms][1] = *(const bf16x8*)(kbase + (long)ms * 16 * H_ + 32);
      va[ms][0] = *(const bf16x8*)(vbase + (long)ms * 16 * SK_);
      va[ms][1] = *(const bf16x8*)(vbase + (long)ms * 16 * SK_ + 32);
    }
    // S^T(64k x 16q) = K_tile @ Q^T ; lane: q=lq, k=ms*16+lh*4+r
    f32x4 s[4];
    __builtin_amdgcn_s_setprio(1);
#pragma unroll
    for (int ms = 0; ms < 4; ++ms) {
      f32x4 z = (f32x4){0.f, 0.f, 0.f, 0.f};
      z = __builtin_amdgcn_mfma_f32_16x16x32_bf16(ka[ms][0], qf0, z, 0, 0, 0);
      z = __builtin_amdgcn_mfma_f32_16x16x32_bf16(ka[ms][1], qf1, z, 0, 0, 0);
      s[ms] = z;
    }
    __builtin_amdgcn_s_setprio(0);
    // no-max softmax: P = exp(s - 16), accumulate l
    float lsum = 0.f;
#pragma unroll
    for (int ms = 0; ms < 4; ++ms) {
      float p0 = exp2f(fmaf(s[ms][0], C1, -C2));
      float p1 = exp2f(fmaf(s[ms][1], C1, -C2));
      float p2 = exp2f(fmaf(s[ms][2], C1, -C2));
      float p3 = exp2f(fmaf(s[ms][3], C1, -C2));
      lsum += (p0 + p1) + (p2 + p3);
      unsigned pk[2] = {pack_bf(p0, p1), pack_bf(p2, p3)};
      *(unsigned long long*)&Pw[sidx(lq, ms * 32 + lh * 8)] =
          *(unsigned long long*)pk;
    }
    l_run += lsum;
    bf16x8 pb0 = *(const bf16x8*)&Pw[sidx(lq, lh * 16)];
    bf16x8 pb1 = *(const bf16x8*)&Pw[sidx(lq, 64 + lh * 16)];
    __builtin_amdgcn_s_setprio(1);
#pragma unroll
    for (int ms = 0; ms < 4; ++ms) {
      accO[ms] = __builtin_amdgcn_mfma_f32_16x16x32_bf16(va[ms][0], pb0, accO[ms], 0, 0, 0);
      accO[ms] = __builtin_amdgcn_mfma_f32_16x16x32_bf16(va[ms][1], pb1, accO[ms], 0, 0, 0);
    }
    __builtin_amdgcn_s_setprio(0);
  }

  l_run += __shfl_xor(l_run, 16);
  l_run += __shfl_xor(l_run, 32);
  float rs = 1.f / l_run;
  long orow = (long)b * SQ_ + qb * 64 + w * 16 + lq;
#pragma unroll
  for (int ms = 0; ms < 4; ++ms) {
    unsigned short ou[4];
#pragma unroll
    for (int r = 0; r < 4; ++r) ou[r] = f2bf(accO[ms][r] * rs);
    *(unsigned long long*)(Ob + orow * H_ + h * HD_ + ms * 16 + lh * 4) =
        *(unsigned long long*)ou;
  }
}

extern "C" void kernel_launch(void* const* d_in, const int* in_sizes, int n_in,
                              void* d_out, int out_size, void* d_ws, size_t ws_size,
                              hipStream_t stream) {
  (void)in_sizes; (void)n_in; (void)out_size; (void)ws_size;
  const float* attender = (const float*)d_in[0];
  const float* attendee = (const float*)d_in[1];
  const int*   mask     = (const int*)d_in[2];
  const float* c_attn_w = (const float*)d_in[3];
  const float* c_attn_b = (const float*)d_in[4];
  const float* c_proj_w = (const float*)d_in[5];
  const float* c_proj_b = (const float*)d_in[6];
  const float* mlp_w    = (const float*)d_in[7];
  const float* mlp_b    = (const float*)d_in[8];
  float* out = (float*)d_out;

  char* ws = (char*)d_ws;
  size_t off = 0;
  auto alloc = [&](size_t bytes) {
    void* p = ws + off;
    off += (bytes + 255) & ~(size_t)255;
    return p;
  };
  unsigned short* cat   = (unsigned short*)alloc((size_t)4096 * 2048 * 2); // [attender_bf | proj_bf]
  unsigned short* aet   = (unsigned short*)alloc((size_t)4096 * 1024 * 2);
  unsigned short* w_atT = (unsigned short*)alloc((size_t)3072 * 1024 * 2); // (3H, H)
  unsigned short* w_prT = (unsigned short*)alloc((size_t)1024 * 1024 * 2);
  unsigned short* w_mlT = (unsigned short*)alloc((size_t)1024 * 2048 * 2); // (H, 2H)
  unsigned short* Qb    = (unsigned short*)alloc((size_t)4096 * 1024 * 2);
  unsigned short* Kbuf  = (unsigned short*)alloc((size_t)4096 * 1024 * 2);
  unsigned short* Vtg   = (unsigned short*)alloc((size_t)B_ * NH_ * HD_ * SK_ * 2);
  unsigned short* attnb = (unsigned short*)alloc((size_t)4096 * 1024 * 2);

  conv_bf16<<<2048, 256, 0, stream>>>(attender, cat, 4096, 1024, 1024, 2048);
  conv_bf16<<<2048, 256, 0, stream>>>(attendee, aet, 4096, 1024, 1024, 1024);
  convT<<<768, 256, 0, stream>>>(c_attn_w, w_atT, 1024, 3072);
  convT<<<256, 256, 0, stream>>>(c_proj_w, w_prT, 1024, 1024);
  convT<<<512, 256, 0, stream>>>(mlp_w, w_mlT, 2048, 1024);

  // Q = attender @ W[:, :H] + b[:H]
  gemm_bt<2, 0><<<dim3(16, 32), 256, 0, stream>>>(
      cat, 2048, w_atT, 1024, c_attn_b, nullptr, Qb, nullptr, 1024, 4096, 1024, 1024);
  // K,V = attendee @ W[:, H:3H] + b[H:3H]; K masked+normal, V transposed
  gemm_bt<4, 2><<<dim3(16, 32), 256, 0, stream>>>(
      aet, 1024, w_atT + (size_t)1024 * 1024, 1024, c_attn_b + 1024, mask,
      Kbuf, Vtg, 1024, 4096, 2048, 1024);
  // attention
  flash_attn<<<dim3(32, 16, 2), 256, 0, stream>>>(Qb, Kbuf, Vtg, attnb);
  // proj -> cat[:, H:2H]
  gemm_bt<2, 0><<<dim3(16, 32), 256, 0, stream>>>(
      attnb, 1024, w_prT, 1024, c_proj_b, nullptr, cat + 1024, nullptr, 2048, 4096, 1024, 1024);
  // out = gelu(cat @ mlp_w + mlp_b), f32
  gemm_bt<2, 1><<<dim3(16, 32), 256, 0, stream>>>(
      cat, 2048, w_mlT, 2048, mlp_b, nullptr, out, nullptr, 1024, 4096, 1024, 2048);
}

// Round 5
// 186.177 us; speedup vs baseline: 1.8462x; 1.8462x over previous
//
#include <hip/hip_runtime.h>
#include <hip/hip_bf16.h>
#include <math.h>

#define H_ 1024
#define NH_ 16
#define HD_ 64
#define B_ 2
#define SQ_ 2048
#define SK_ 2048

using bf16x8 = __attribute__((ext_vector_type(8))) short;
using f32x4  = __attribute__((ext_vector_type(4))) float;

static __device__ __forceinline__ unsigned short f2bf(float f) {
  union { float f; unsigned u; } v; v.f = f;
  unsigned r = v.u + 0x7fffu + ((v.u >> 16) & 1u);
  return (unsigned short)(r >> 16);
}

// pack two f32 -> two bf16 (round-half-up) in one dword: [a(lo), b(hi)]
static __device__ __forceinline__ unsigned pack_bf(float a, float b) {
  union { float f; unsigned u; } ua, ub;
  ua.f = a; ub.f = b;
  return __builtin_amdgcn_perm(ub.u + 0x8000u, ua.u + 0x8000u, 0x07060302u);
}

static __device__ __forceinline__ void gl2lds16(const void* g, void* l) {
  __builtin_amdgcn_global_load_lds(
      (const __attribute__((address_space(1))) unsigned int*)g,
      (__attribute__((address_space(3))) unsigned int*)l, 16, 0, 0);
}

// swizzled index (shorts) within a [rows][64-short] tile, 128B rows
static __device__ __forceinline__ int sidx(int row, int cbyte) {
  return row * 64 + (((cbyte) ^ ((row & 7) << 4)) >> 1);
}

// ---------------- f32 -> bf16 convert (8 elems/thread) ----------------
__global__ __launch_bounds__(256) void conv_bf16(
    const float* __restrict__ src, unsigned short* __restrict__ dst,
    int rows, int cols, int ld_src, int ld_dst) {
  long total = (long)rows * cols / 8;
  for (long i = blockIdx.x * (long)blockDim.x + threadIdx.x; i < total;
       i += (long)gridDim.x * blockDim.x) {
    long e = i * 8;
    int r = (int)(e / cols);
    int c = (int)(e % cols);
    const float* s = src + (long)r * ld_src + c;
    unsigned short tmp[8];
#pragma unroll
    for (int j = 0; j < 8; ++j) tmp[j] = f2bf(s[j]);
    *(uint4*)(dst + (long)r * ld_dst + c) = *(uint4*)tmp;
  }
}

// ---------------- f32 (R,C) -> bf16 transposed (C,R) ----------------
__global__ __launch_bounds__(256) void convT(
    const float* __restrict__ in, unsigned short* __restrict__ out, int R, int C) {
  __shared__ __align__(16) unsigned short Ls[64][68];
  int nct = C >> 6;
  int tr = blockIdx.x / nct, tc = blockIdx.x % nct;
  int r0 = tr * 64, c0 = tc * 64;
  int rr = threadIdx.x >> 4;
  int cc = (threadIdx.x & 15) * 4;
#pragma unroll
  for (int i = 0; i < 4; ++i) {
    int r = rr + 16 * i;
    float4 v = *(const float4*)&in[(long)(r0 + r) * C + c0 + cc];
    unsigned short t[4] = {f2bf(v.x), f2bf(v.y), f2bf(v.z), f2bf(v.w)};
    *(unsigned long long*)&Ls[r][cc] = *(unsigned long long*)t;
  }
  __syncthreads();
  int oc = threadIdx.x >> 2;
  int orr = (threadIdx.x & 3) * 16;
  unsigned short t[16];
#pragma unroll
  for (int j = 0; j < 16; ++j) t[j] = Ls[orr + j][oc];
  *(uint4*)&out[(long)(c0 + oc) * R + r0 + orr] = *(uint4*)&t[0];
  *(uint4*)&out[(long)(c0 + oc) * R + r0 + orr + 8] = *(uint4*)&t[8];
}

// ---------------- bf16 GEMM, B^T input, BK=64, double-buffered, swizzled ----
// Out = A(MxK) @ W(KxN) + bias, Bw = W^T (N rows, K cols). BN = NF*32.
// MODE 0: bf16 out0.  MODE 1: f32 out0 + GELU.  MODE 2: split KV (col<H ->
// bf16 K*mask to out0; col>=H -> V transposed to out1 (B,NH,HD,SK)).
template <int NF, int MODE>
__global__ __launch_bounds__(256) void gemm_bt(
    const unsigned short* __restrict__ A, int lda,
    const unsigned short* __restrict__ Bw, int ldb,
    const float* __restrict__ bias, const int* __restrict__ msk,
    void* __restrict__ out0, void* __restrict__ out1, int ldo,
    int M, int N, int K) {
  __shared__ __align__(16) unsigned short Al[2][128 * 64];
  __shared__ __align__(16) unsigned short Bl[2][NF * 32 * 64];
  const int tid = threadIdx.x;
  const int l = tid & 63, w = tid >> 6;
  const int wr = w >> 1, wc = w & 1;
  const int lq = l & 15, lh = l >> 4;
  const int m0 = blockIdx.y * 128, n0 = blockIdx.x * (NF * 32);

  // pre-swizzled global source (rule #21: linear LDS dest + inv-swizzled src)
  const int swcol = (((tid & 7) ^ ((tid >> 3) & 7)) << 3);  // shorts
  const int rbase = w * 8 + (l >> 3);
  const unsigned short* gA = A + (long)(m0 + rbase) * lda + swcol;
  const unsigned short* gB = Bw + (long)(n0 + rbase) * ldb + swcol;

  f32x4 acc[4][NF];
#pragma unroll
  for (int a = 0; a < 4; ++a)
#pragma unroll
    for (int b = 0; b < NF; ++b) acc[a][b] = (f32x4){0.f, 0.f, 0.f, 0.f};

  auto stage = [&](int k0, int buf) {
#pragma unroll
    for (int i = 0; i < 4; ++i)
      gl2lds16(gA + (long)(i * 32) * lda + k0, &Al[buf][i * 2048 + w * 512]);
#pragma unroll
    for (int i = 0; i < NF; ++i)
      gl2lds16(gB + (long)(i * 32) * ldb + k0, &Bl[buf][i * 2048 + w * 512]);
  };

  const int NT = K >> 6;
  stage(0, 0);
  __syncthreads();
  int cur = 0;
  for (int t = 0; t < NT; ++t) {
    if (t + 1 < NT) stage((t + 1) << 6, cur ^ 1);
    bf16x8 af[4][2], bfr[NF][2];
#pragma unroll
    for (int a = 0; a < 4; ++a) {
      int row = wr * 64 + a * 16 + lq;
#pragma unroll
      for (int kk = 0; kk < 2; ++kk)
        af[a][kk] = *(const bf16x8*)&Al[cur][sidx(row, kk * 64 + lh * 16)];
    }
#pragma unroll
    for (int b = 0; b < NF; ++b) {
      int row = wc * (NF * 16) + b * 16 + lq;
#pragma unroll
      for (int kk = 0; kk < 2; ++kk)
        bfr[b][kk] = *(const bf16x8*)&Bl[cur][sidx(row, kk * 64 + lh * 16)];
    }
#pragma unroll
    for (int kk = 0; kk < 2; ++kk)
#pragma unroll
      for (int a = 0; a < 4; ++a)
#pragma unroll
        for (int b = 0; b < NF; ++b)
          acc[a][b] = __builtin_amdgcn_mfma_f32_16x16x32_bf16(
              af[a][kk], bfr[b][kk], acc[a][b], 0, 0, 0);
    __syncthreads();
    cur ^= 1;
  }

#pragma unroll
  for (int a = 0; a < 4; ++a) {
#pragma unroll
    for (int bb = 0; bb < NF; ++bb) {
      int col = n0 + wc * (NF * 16) + bb * 16 + lq;
      float bv = bias[col];
      int row0 = m0 + wr * 64 + a * 16 + lh * 4;
      if (MODE == 0) {
        unsigned short* O = (unsigned short*)out0;
#pragma unroll
        for (int r = 0; r < 4; ++r)
          O[(long)(row0 + r) * ldo + col] = f2bf(acc[a][bb][r] + bv);
      } else if (MODE == 1) {
        float* O = (float*)out0;
#pragma unroll
        for (int r = 0; r < 4; ++r) {
          float v = acc[a][bb][r] + bv;
          float y = 0.7978845608028654f * (v + 0.044715f * v * v * v);
          O[(long)(row0 + r) * ldo + col] =
              v * __builtin_amdgcn_rcpf(1.f + __expf(-2.f * y));
        }
      } else {
        if (col < H_) {
          // K output, pre-masked: k-row index is row0+r (= b*SK + k)
          unsigned short* O = (unsigned short*)out0;
#pragma unroll
          for (int r = 0; r < 4; ++r) {
            float mk = (float)msk[row0 + r];
            O[(long)(row0 + r) * ldo + col] = f2bf((acc[a][bb][r] + bv) * mk);
          }
        } else {
          int vcol = col - H_, hh = vcol >> 6, dd = vcol & 63;
          int bi = row0 >> 11, k = row0 & 2047;
          unsigned short t[4];
#pragma unroll
          for (int r = 0; r < 4; ++r) t[r] = f2bf(acc[a][bb][r] + bv);
          *(unsigned long long*)((unsigned short*)out1 +
                                 (((long)(bi * NH_ + hh) * HD_ + dd) << 11) + k) =
              *(unsigned long long*)t;
        }
      }
    }
  }
}

// ---------------- flash attention: LDS+swizzle staging, no-max softmax ------
// grid (SQ/64, NH, B), block 256 = 4 waves x 16 q-rows. KV tiles of 64.
// K pre-masked (B*SK, H); V pre-transposed (B, NH, HD, SK).
__global__ __launch_bounds__(256) void flash_attn(
    const unsigned short* __restrict__ Qb,
    const unsigned short* __restrict__ Kb,
    const unsigned short* __restrict__ Vtg,
    unsigned short* __restrict__ Ob) {
  __shared__ __align__(16) unsigned short Kl[64 * 64];
  __shared__ __align__(16) unsigned short Vt[64 * 64];  // Vt[d][k]
  __shared__ __align__(16) unsigned short Pl[4][1024];
  const int tid = threadIdx.x;
  const int l = tid & 63, w = tid >> 6;
  const int qb = blockIdx.x, h = blockIdx.y, b = blockIdx.z;
  const int lq = l & 15, lh = l >> 4;

  const long qrow = (long)b * SQ_ + qb * 64 + w * 16 + lq;
  const unsigned short* qp = Qb + qrow * H_ + h * HD_;
  const bf16x8 qf0 = *(const bf16x8*)(qp + lh * 8);
  const bf16x8 qf1 = *(const bf16x8*)(qp + 32 + lh * 8);

  const int sr = tid >> 2, scs = (tid & 3) * 16;
  const unsigned short* Kg = Kb + ((long)b * SK_ + sr) * H_ + h * HD_ + scs;
  const unsigned short* Vg = Vtg + ((long)(b * NH_ + h) * HD_ + sr) * SK_ + scs;
  const int wi0 = sidx(sr, (tid & 3) * 32);
  const int wi1 = sidx(sr, (tid & 3) * 32 + 16);

  // prologue: tile 0 into regs, then LDS
  uint4 kr0 = *(const uint4*)Kg, kr1 = *(const uint4*)(Kg + 8);
  uint4 vr0 = *(const uint4*)Vg, vr1 = *(const uint4*)(Vg + 8);
  *(uint4*)&Kl[wi0] = kr0;
  *(uint4*)&Kl[wi1] = kr1;
  *(uint4*)&Vt[wi0] = vr0;
  *(uint4*)&Vt[wi1] = vr1;

  unsigned short* Pw = Pl[w];
  const float C1 = 1.4426950408889634f;   // 1/ln2
  const float C2 = 23.083120654223414f;   // 16/ln2  (P = exp(s-16))

  float l_run = 0.f;
  f32x4 accO[4];
#pragma unroll
  for (int ms = 0; ms < 4; ++ms) accO[ms] = (f32x4){0.f, 0.f, 0.f, 0.f};

  const int NT = SK_ / 64;
  for (int kt = 0; kt < NT; ++kt) {
    __syncthreads();  // staged tile visible
    if (kt + 1 < NT) {  // prefetch next tile into regs (overlaps compute)
      const unsigned short* kp = Kg + (long)(kt + 1) * 64 * H_;
      kr0 = *(const uint4*)kp;
      kr1 = *(const uint4*)(kp + 8);
      vr0 = *(const uint4*)(Vg + (kt + 1) * 64);
      vr1 = *(const uint4*)(Vg + (kt + 1) * 64 + 8);
    }

    // S^T(64k x 16q) = K_tile @ Q^T ; lane: q=lq, k=ms*16+lh*4+r
    f32x4 s[4];
    __builtin_amdgcn_s_setprio(1);
#pragma unroll
    for (int ms = 0; ms < 4; ++ms) {
      int row = ms * 16 + lq;
      bf16x8 a0 = *(const bf16x8*)&Kl[sidx(row, lh * 16)];
      bf16x8 a1 = *(const bf16x8*)&Kl[sidx(row, 64 + lh * 16)];
      f32x4 z = (f32x4){0.f, 0.f, 0.f, 0.f};
      z = __builtin_amdgcn_mfma_f32_16x16x32_bf16(a0, qf0, z, 0, 0, 0);
      z = __builtin_amdgcn_mfma_f32_16x16x32_bf16(a1, qf1, z, 0, 0, 0);
      s[ms] = z;
    }
    __builtin_amdgcn_s_setprio(0);
    // no-max softmax: P = exp(s - 16), accumulate l
#pragma unroll
    for (int ms = 0; ms < 4; ++ms) {
      float p0 = exp2f(fmaf(s[ms][0], C1, -C2));
      float p1 = exp2f(fmaf(s[ms][1], C1, -C2));
      float p2 = exp2f(fmaf(s[ms][2], C1, -C2));
      float p3 = exp2f(fmaf(s[ms][3], C1, -C2));
      l_run += (p0 + p1) + (p2 + p3);
      unsigned pk[2] = {pack_bf(p0, p1), pack_bf(p2, p3)};
      *(unsigned long long*)&Pw[sidx(lq, ms * 32 + lh * 8)] =
          *(unsigned long long*)pk;
    }
    bf16x8 pb0 = *(const bf16x8*)&Pw[sidx(lq, lh * 16)];
    bf16x8 pb1 = *(const bf16x8*)&Pw[sidx(lq, 64 + lh * 16)];
    __builtin_amdgcn_s_setprio(1);
#pragma unroll
    for (int ms = 0; ms < 4; ++ms) {
      int row = ms * 16 + lq;
      bf16x8 v0 = *(const bf16x8*)&Vt[sidx(row, lh * 16)];
      bf16x8 v1 = *(const bf16x8*)&Vt[sidx(row, 64 + lh * 16)];
      accO[ms] = __builtin_amdgcn_mfma_f32_16x16x32_bf16(v0, pb0, accO[ms], 0, 0, 0);
      accO[ms] = __builtin_amdgcn_mfma_f32_16x16x32_bf16(v1, pb1, accO[ms], 0, 0, 0);
    }
    __builtin_amdgcn_s_setprio(0);
    __syncthreads();  // all reads of this tile done
    if (kt + 1 < NT) {
      *(uint4*)&Kl[wi0] = kr0;
      *(uint4*)&Kl[wi1] = kr1;
      *(uint4*)&Vt[wi0] = vr0;
      *(uint4*)&Vt[wi1] = vr1;
    }
  }

  l_run += __shfl_xor(l_run, 16);
  l_run += __shfl_xor(l_run, 32);
  float rs = 1.f / l_run;
  long orow = (long)b * SQ_ + qb * 64 + w * 16 + lq;
#pragma unroll
  for (int ms = 0; ms < 4; ++ms) {
    unsigned short ou[4];
#pragma unroll
    for (int r = 0; r < 4; ++r) ou[r] = f2bf(accO[ms][r] * rs);
    *(unsigned long long*)(Ob + orow * H_ + h * HD_ + ms * 16 + lh * 4) =
        *(unsigned long long*)ou;
  }
}

extern "C" void kernel_launch(void* const* d_in, const int* in_sizes, int n_in,
                              void* d_out, int out_size, void* d_ws, size_t ws_size,
                              hipStream_t stream) {
  (void)in_sizes; (void)n_in; (void)out_size; (void)ws_size;
  const float* attender = (const float*)d_in[0];
  const float* attendee = (const float*)d_in[1];
  const int*   mask     = (const int*)d_in[2];
  const float* c_attn_w = (const float*)d_in[3];
  const float* c_attn_b = (const float*)d_in[4];
  const float* c_proj_w = (const float*)d_in[5];
  const float* c_proj_b = (const float*)d_in[6];
  const float* mlp_w    = (const float*)d_in[7];
  const float* mlp_b    = (const float*)d_in[8];
  float* out = (float*)d_out;

  char* ws = (char*)d_ws;
  size_t off = 0;
  auto alloc = [&](size_t bytes) {
    void* p = ws + off;
    off += (bytes + 255) & ~(size_t)255;
    return p;
  };
  unsigned short* cat   = (unsigned short*)alloc((size_t)4096 * 2048 * 2); // [attender_bf | proj_bf]
  unsigned short* aet   = (unsigned short*)alloc((size_t)4096 * 1024 * 2);
  unsigned short* w_atT = (unsigned short*)alloc((size_t)3072 * 1024 * 2); // (3H, H)
  unsigned short* w_prT = (unsigned short*)alloc((size_t)1024 * 1024 * 2);
  unsigned short* w_mlT = (unsigned short*)alloc((size_t)1024 * 2048 * 2); // (H, 2H)
  unsigned short* Qb    = (unsigned short*)alloc((size_t)4096 * 1024 * 2);
  unsigned short* Kbuf  = (unsigned short*)alloc((size_t)4096 * 1024 * 2);
  unsigned short* Vtg   = (unsigned short*)alloc((size_t)B_ * NH_ * HD_ * SK_ * 2);
  unsigned short* attnb = (unsigned short*)alloc((size_t)4096 * 1024 * 2);

  conv_bf16<<<2048, 256, 0, stream>>>(attender, cat, 4096, 1024, 1024, 2048);
  conv_bf16<<<2048, 256, 0, stream>>>(attendee, aet, 4096, 1024, 1024, 1024);
  convT<<<768, 256, 0, stream>>>(c_attn_w, w_atT, 1024, 3072);
  convT<<<256, 256, 0, stream>>>(c_proj_w, w_prT, 1024, 1024);
  convT<<<512, 256, 0, stream>>>(mlp_w, w_mlT, 2048, 1024);

  // Q = attender @ W[:, :H] + b[:H]
  gemm_bt<2, 0><<<dim3(16, 32), 256, 0, stream>>>(
      cat, 2048, w_atT, 1024, c_attn_b, nullptr, Qb, nullptr, 1024, 4096, 1024, 1024);
  // K,V = attendee @ W[:, H:3H] + b[H:3H]; K masked+normal, V transposed
  gemm_bt<4, 2><<<dim3(16, 32), 256, 0, stream>>>(
      aet, 1024, w_atT + (size_t)1024 * 1024, 1024, c_attn_b + 1024, mask,
      Kbuf, Vtg, 1024, 4096, 2048, 1024);
  // attention
  flash_attn<<<dim3(32, 16, 2), 256, 0, stream>>>(Qb, Kbuf, Vtg, attnb);
  // proj -> cat[:, H:2H]
  gemm_bt<2, 0><<<dim3(16, 32), 256, 0, stream>>>(
      attnb, 1024, w_prT, 1024, c_proj_b, nullptr, cat + 1024, nullptr, 2048, 4096, 1024, 1024);
  // out = gelu(cat @ mlp_w + mlp_b), f32
  gemm_bt<2, 1><<<dim3(16, 32), 256, 0, stream>>>(
      cat, 2048, w_mlT, 2048, mlp_b, nullptr, out, nullptr, 1024, 4096, 1024, 2048);
}